// Round 1
// baseline (9277.101 us; speedup 1.0000x reference)
//
#include <hip/hip_runtime.h>
#include <hip/hip_bf16.h>

#define MLP_ROWS 32

// ---------------------------------------------------------------------------
// scatter-add: agg[dst] += feat[src], one thread per (edge, 4-float chunk)
// ---------------------------------------------------------------------------
__global__ __launch_bounds__(256) void scatter_add_k(
    const float* __restrict__ feat, const int* __restrict__ esrc,
    const int* __restrict__ edst, float* __restrict__ agg, int total)
{
    int i = blockIdx.x * 256 + threadIdx.x;
    if (i >= total) return;
    int e = i >> 5;              // edge index
    int c = (i & 31) << 2;       // float offset within the 128-wide row
    int s = esrc[e];
    int d = edst[e];
    float4 v = *reinterpret_cast<const float4*>(&feat[(size_t)s * 128 + c]);
    float* p = &agg[(size_t)d * 128 + c];
    atomicAdd(p + 0, v.x);
    atomicAdd(p + 1, v.y);
    atomicAdd(p + 2, v.z);
    atomicAdd(p + 3, v.w);
}

// ---------------------------------------------------------------------------
// MLP helpers
// ---------------------------------------------------------------------------
__device__ __forceinline__ void stage_w(float* Wl, const float* __restrict__ Wsrc, int t)
{
    // 64 rows x 128 cols = 8192 floats; 256 threads x float4 -> 8 iterations
    for (int i = t * 4; i < 8192; i += 1024)
        *reinterpret_cast<float4*>(&Wl[i]) = *reinterpret_cast<const float4*>(&Wsrc[i]);
}

__device__ __forceinline__ void gemm_half(const float* __restrict__ Wl,
                                          const float* __restrict__ ta,
                                          int ty, int tx, int kbase, float acc[2][8])
{
    for (int k = 0; k < 64; k += 4) {
        float4 a0 = *reinterpret_cast<const float4*>(&ta[(ty * 2 + 0) * 132 + kbase + k]);
        float4 a1 = *reinterpret_cast<const float4*>(&ta[(ty * 2 + 1) * 132 + kbase + k]);
        const float* a0p = reinterpret_cast<const float*>(&a0);
        const float* a1p = reinterpret_cast<const float*>(&a1);
#pragma unroll
        for (int kk = 0; kk < 4; ++kk) {
            float4 b0 = *reinterpret_cast<const float4*>(&Wl[(k + kk) * 128 + tx * 8]);
            float4 b1 = *reinterpret_cast<const float4*>(&Wl[(k + kk) * 128 + tx * 8 + 4]);
            float av0 = a0p[kk], av1 = a1p[kk];
            acc[0][0] += av0 * b0.x; acc[0][1] += av0 * b0.y;
            acc[0][2] += av0 * b0.z; acc[0][3] += av0 * b0.w;
            acc[0][4] += av0 * b1.x; acc[0][5] += av0 * b1.y;
            acc[0][6] += av0 * b1.z; acc[0][7] += av0 * b1.w;
            acc[1][0] += av1 * b0.x; acc[1][1] += av1 * b0.y;
            acc[1][2] += av1 * b0.z; acc[1][3] += av1 * b0.w;
            acc[1][4] += av1 * b1.x; acc[1][5] += av1 * b1.y;
            acc[1][6] += av1 * b1.z; acc[1][7] += av1 * b1.w;
        }
    }
}

// ---------------------------------------------------------------------------
// fused MLP: out = relu(relu((x+agg)@Wa + ba)@Wb + bb); also per-col sum/sumsq
// 32 rows per block, 256 threads = 16x16 grid, each thread 2 rows x 8 cols.
// Weights staged in LDS in 64-row halves (LDS ~50KB -> 3 blocks/CU).
// ---------------------------------------------------------------------------
__global__ __launch_bounds__(256) void mlp_k(
    const float* __restrict__ xin, const float* __restrict__ agg,
    const float* __restrict__ Wa, const float* __restrict__ ba,
    const float* __restrict__ Wb, const float* __restrict__ bb,
    float* __restrict__ out, float* __restrict__ stats, int N)
{
    __shared__ float Wl[64 * 128];        // 32 KB (one K-half of a weight mat)
    __shared__ float ta[MLP_ROWS * 132];  // 16.9 KB, pad 132 kills A-read conflicts
    __shared__ float ssum[256];           // col sums (0..127) + sumsq (128..255)

    int t = threadIdx.x;
    int row0 = blockIdx.x * MLP_ROWS;
    int tx = t & 15;   // col group: 8 contiguous cols at tx*8
    int ty = t >> 4;   // rows ty*2, ty*2+1

    // stage input tile = x + agg
    for (int i = t * 4; i < MLP_ROWS * 128; i += 1024) {
        int r = i >> 7, c = i & 127;
        float4 v;
        if (row0 + r < N) {
            size_t g = (size_t)(row0 + r) * 128 + c;
            v = *reinterpret_cast<const float4*>(&xin[g]);
            float4 av = *reinterpret_cast<const float4*>(&agg[g]);
            v.x += av.x; v.y += av.y; v.z += av.z; v.w += av.w;
        } else {
            v = make_float4(0.f, 0.f, 0.f, 0.f);
        }
        *reinterpret_cast<float4*>(&ta[r * 132 + c]) = v;
    }
    stage_w(Wl, Wa, t);
    ssum[t] = 0.0f;
    __syncthreads();

    float acc[2][8];
#pragma unroll
    for (int j = 0; j < 8; ++j) { float b = ba[tx * 8 + j]; acc[0][j] = b; acc[1][j] = b; }
    gemm_half(Wl, ta, ty, tx, 0, acc);
    __syncthreads();
    stage_w(Wl, Wa + 64 * 128, t);
    __syncthreads();
    gemm_half(Wl, ta, ty, tx, 64, acc);
    __syncthreads();   // everyone done reading ta and Wl

    // relu, write intermediate back into ta
#pragma unroll
    for (int i = 0; i < 2; ++i) {
#pragma unroll
        for (int j = 0; j < 8; ++j) acc[i][j] = fmaxf(acc[i][j], 0.0f);
        *reinterpret_cast<float4*>(&ta[(ty * 2 + i) * 132 + tx * 8]) =
            make_float4(acc[i][0], acc[i][1], acc[i][2], acc[i][3]);
        *reinterpret_cast<float4*>(&ta[(ty * 2 + i) * 132 + tx * 8 + 4]) =
            make_float4(acc[i][4], acc[i][5], acc[i][6], acc[i][7]);
    }
    stage_w(Wl, Wb, t);
    __syncthreads();

#pragma unroll
    for (int j = 0; j < 8; ++j) { float b = bb[tx * 8 + j]; acc[0][j] = b; acc[1][j] = b; }
    gemm_half(Wl, ta, ty, tx, 0, acc);
    __syncthreads();
    stage_w(Wl, Wb + 64 * 128, t);
    __syncthreads();
    gemm_half(Wl, ta, ty, tx, 64, acc);

    // relu + write out + BN stats
#pragma unroll
    for (int i = 0; i < 2; ++i) {
        int r = row0 + ty * 2 + i;
        if (r < N) {
#pragma unroll
            for (int j = 0; j < 8; ++j) acc[i][j] = fmaxf(acc[i][j], 0.0f);
            *reinterpret_cast<float4*>(&out[(size_t)r * 128 + tx * 8]) =
                make_float4(acc[i][0], acc[i][1], acc[i][2], acc[i][3]);
            *reinterpret_cast<float4*>(&out[(size_t)r * 128 + tx * 8 + 4]) =
                make_float4(acc[i][4], acc[i][5], acc[i][6], acc[i][7]);
#pragma unroll
            for (int j = 0; j < 8; ++j) {
                int c = tx * 8 + j;
                atomicAdd(&ssum[c], acc[i][j]);
                atomicAdd(&ssum[128 + c], acc[i][j] * acc[i][j]);
            }
        }
    }
    __syncthreads();
    atomicAdd(&stats[t], ssum[t]);
}

// ---------------------------------------------------------------------------
// BatchNorm apply (in place): h = (h - mean) * gamma * rsqrt(var+eps) + beta
// ---------------------------------------------------------------------------
__global__ __launch_bounds__(256) void bn_apply_k(
    float* __restrict__ h, const float* __restrict__ stats,
    const float* __restrict__ gamma, const float* __restrict__ beta, int N)
{
    __shared__ float sc[128], sh[128];
    int t = threadIdx.x;
    if (t < 128) {
        float invN = 1.0f / (float)N;
        float mean = stats[t] * invN;
        float var  = stats[128 + t] * invN - mean * mean;
        float s = gamma[t] * rsqrtf(var + 1e-5f);
        sc[t] = s;
        sh[t] = beta[t] - mean * s;
    }
    __syncthreads();
    int total = N * 32;  // float4 count
    for (int i = blockIdx.x * 256 + t; i < total; i += gridDim.x * 256) {
        float4 v = reinterpret_cast<float4*>(h)[i];
        int c = (i & 31) * 4;
        v.x = v.x * sc[c + 0] + sh[c + 0];
        v.y = v.y * sc[c + 1] + sh[c + 1];
        v.z = v.z * sc[c + 2] + sh[c + 2];
        v.w = v.w * sc[c + 3] + sh[c + 3];
        reinterpret_cast<float4*>(h)[i] = v;
    }
}

// ---------------------------------------------------------------------------
extern "C" void kernel_launch(void* const* d_in, const int* in_sizes, int n_in,
                              void* d_out, int out_size, void* d_ws, size_t ws_size,
                              hipStream_t stream)
{
    const float* x   = (const float*)d_in[0];
    const int*   ei  = (const int*)d_in[1];
    const float* W1a = (const float*)d_in[2];
    const float* b1a = (const float*)d_in[3];
    const float* W1b = (const float*)d_in[4];
    const float* b1b = (const float*)d_in[5];
    const float* g1  = (const float*)d_in[6];
    const float* be1 = (const float*)d_in[7];
    const float* W2a = (const float*)d_in[8];
    const float* b2a = (const float*)d_in[9];
    const float* W2b = (const float*)d_in[10];
    const float* b2b = (const float*)d_in[11];
    const float* g2  = (const float*)d_in[12];
    const float* be2 = (const float*)d_in[13];

    const int N = in_sizes[0] / 128;
    const int E = in_sizes[1] / 2;
    const int* esrc = ei;
    const int* edst = ei + E;

    float* agg   = (float*)d_ws;
    float* stats = (float*)((char*)d_ws + (size_t)N * 128 * sizeof(float));
    float* out   = (float*)d_out;

    const size_t zero_bytes = (size_t)N * 128 * sizeof(float) + 1024;
    const int stotal  = E * 32;
    const int sblocks = (stotal + 255) / 256;
    const int mblocks = (N + MLP_ROWS - 1) / MLP_ROWS;

    // ---- layer 1 ----
    hipMemsetAsync(d_ws, 0, zero_bytes, stream);
    scatter_add_k<<<sblocks, 256, 0, stream>>>(x, esrc, edst, agg, stotal);
    mlp_k<<<mblocks, 256, 0, stream>>>(x, agg, W1a, b1a, W1b, b1b, out, stats, N);
    bn_apply_k<<<2048, 256, 0, stream>>>(out, stats, g1, be1, N);

    // ---- layer 2 ----
    hipMemsetAsync(d_ws, 0, zero_bytes, stream);
    scatter_add_k<<<sblocks, 256, 0, stream>>>(out, esrc, edst, agg, stotal);
    mlp_k<<<mblocks, 256, 0, stream>>>(out, agg, W2a, b2a, W2b, b2b, out, stats, N);
    bn_apply_k<<<2048, 256, 0, stream>>>(out, stats, g2, be2, N);
}

// Round 2
// 562.728 us; speedup vs baseline: 16.4859x; 16.4859x over previous
//
#include <hip/hip_runtime.h>
#include <hip/hip_bf16.h>

typedef unsigned int u32;
typedef unsigned short u16;
typedef short bf16x8 __attribute__((ext_vector_type(8)));
typedef float f32x4 __attribute__((ext_vector_type(4)));

static __device__ __forceinline__ float bf_lo(u32 v) { return __uint_as_float(v << 16); }
static __device__ __forceinline__ float bf_hi(u32 v) { return __uint_as_float(v & 0xffff0000u); }
static __device__ __forceinline__ u16 f2bf(float f) {
    u32 u = __float_as_uint(f);
    u32 r = u + 0x7fffu + ((u >> 16) & 1u);   // RNE; inputs finite
    return (u16)(r >> 16);
}
static __device__ __forceinline__ u32 pack2(float a, float b) {
    return ((u32)f2bf(b) << 16) | (u32)f2bf(a);
}

// ---------------------------------------------------------------------------
// f32 -> bf16 convert (row-major, packed pairs)
// ---------------------------------------------------------------------------
__global__ __launch_bounds__(256) void convert_k(const float* __restrict__ in,
                                                 u32* __restrict__ out2, int total4)
{
    for (int i = blockIdx.x * 256 + threadIdx.x; i < total4; i += gridDim.x * 256) {
        float4 v = reinterpret_cast<const float4*>(in)[i];
        out2[2 * i + 0] = pack2(v.x, v.y);
        out2[2 * i + 1] = pack2(v.z, v.w);
    }
}

// ---------------------------------------------------------------------------
// weight prep: W (128x128 f32, row-major W[k][n]) -> fragment-ordered bf16
// Wf[((kg*8+nb)*64 + l)*8 + j] = W[kg*32 + (l>>4)*8 + j][nb*16 + (l&15)]
// ---------------------------------------------------------------------------
__global__ __launch_bounds__(256) void wprep_k(const float* __restrict__ W,
                                               u16* __restrict__ Wf)
{
    int t = blockIdx.x * 256 + threadIdx.x;   // 0..16383
    int j  = t & 7;
    int l  = (t >> 3) & 63;
    int nb = (t >> 9) & 7;
    int kg = (t >> 12) & 3;
    int k  = kg * 32 + (l >> 4) * 8 + j;
    int n  = nb * 16 + (l & 15);
    Wf[t] = f2bf(W[k * 128 + n]);
}

// ---------------------------------------------------------------------------
// CSR build
// ---------------------------------------------------------------------------
__global__ __launch_bounds__(256) void count_k(const int* __restrict__ edst,
                                               int* __restrict__ deg, int E)
{
    int i = blockIdx.x * 256 + threadIdx.x;
    if (i < E) atomicAdd(&deg[edst[i]], 1);
}

__global__ __launch_bounds__(256) void scan1_k(const int* __restrict__ deg,
                                               int* __restrict__ offs,
                                               int* __restrict__ bsum, int N)
{
    __shared__ int s[256];
    int t = threadIdx.x, i = blockIdx.x * 256 + t;
    int v = (i < N) ? deg[i] : 0;
    s[t] = v; __syncthreads();
    for (int d = 1; d < 256; d <<= 1) {
        int x = (t >= d) ? s[t - d] : 0;
        __syncthreads();
        s[t] += x;
        __syncthreads();
    }
    if (i < N) offs[i] = s[t] - v;
    if (t == 255) bsum[blockIdx.x] = s[255];
}

__global__ __launch_bounds__(512) void scan2_k(int* __restrict__ bsum, int nb)
{
    __shared__ int s[512];
    int t = threadIdx.x;
    int v = (t < nb) ? bsum[t] : 0;
    s[t] = v; __syncthreads();
    for (int d = 1; d < 512; d <<= 1) {
        int x = (t >= d) ? s[t - d] : 0;
        __syncthreads();
        s[t] += x;
        __syncthreads();
    }
    if (t < nb) bsum[t] = s[t] - v;
}

__global__ __launch_bounds__(256) void scan3_k(int* __restrict__ offs,
                                               const int* __restrict__ bsum,
                                               int* __restrict__ cur, int N)
{
    int i = blockIdx.x * 256 + threadIdx.x;
    if (i < N) {
        int o = offs[i] + bsum[blockIdx.x];
        offs[i] = o;
        cur[i] = o;
    }
}

__global__ __launch_bounds__(256) void fill_k(const int* __restrict__ esrc,
                                              const int* __restrict__ edst,
                                              int* __restrict__ cur,
                                              int* __restrict__ slots, int E)
{
    int i = blockIdx.x * 256 + threadIdx.x;
    if (i < E) {
        int d = edst[i];
        int p = atomicAdd(&cur[d], 1);
        slots[p] = esrc[i];
    }
}

// ---------------------------------------------------------------------------
// gather-aggregate: xa[row] = bf16( xb[row] + sum_{s in nbrs(row)} xb[s] )
// one wave per row; lane owns 2 cols (one u32 of packed bf16)
// ---------------------------------------------------------------------------
__global__ __launch_bounds__(256) void gather_k(const u32* __restrict__ xb2,
                                                const int* __restrict__ offs,
                                                const int* __restrict__ deg,
                                                const int* __restrict__ slots,
                                                u32* __restrict__ xa2, int N)
{
    int row = blockIdx.x * 4 + (threadIdx.x >> 6);
    if (row >= N) return;
    int lane = threadIdx.x & 63;

    u32 self = xb2[(size_t)row * 64 + lane];
    float ax = bf_lo(self), ay = bf_hi(self);

    int start = offs[row];
    int dg = deg[row];
    for (int base = 0; base < dg; base += 64) {
        int rem = dg - base;
        int m = rem < 64 ? rem : 64;
        int slot = (lane < m) ? slots[start + base + lane] : 0;
        for (int j = 0; j < m; ++j) {
            int s = __shfl(slot, j);
            u32 v = xb2[(size_t)s * 64 + lane];
            ax += bf_lo(v);
            ay += bf_hi(v);
        }
    }
    xa2[(size_t)row * 64 + lane] = pack2(ax, ay);
}

// ---------------------------------------------------------------------------
// fused MFMA MLP: h = relu(relu(XA@Wa + ba)@Wb + bb), + per-col sum/sumsq
// block = 256 thr = 4 waves, 64 rows x 128 cols. Wave w owns cols w*32..+31.
// LDS tiles XOR-swizzled: short idx ^= (row&7)<<3  (conflict-free b128 reads)
// ---------------------------------------------------------------------------
__global__ __launch_bounds__(256) void mlp_mfma_k(
    const u16* __restrict__ xa,
    const u16* __restrict__ wfa, const float* __restrict__ ba,
    const u16* __restrict__ wfb, const float* __restrict__ bb,
    float* __restrict__ h, float* __restrict__ stats, int N)
{
    __shared__ short ta[64 * 128];   // 16 KB input tile (bf16, swizzled)
    __shared__ short tc[64 * 128];   // 16 KB intermediate tile
    __shared__ float ssum[256];

    int t = threadIdx.x;
    int w = t >> 6, l = t & 63;
    int row0 = blockIdx.x * 64;

    // stage XA tile (swizzled)
    for (int c = t; c < 1024; c += 256) {
        int r = c >> 4, ci = c & 15;
        int dst = (r * 128 + ci * 8) ^ ((r & 7) << 3);
        f32x4 v;
        if (row0 + r < N)
            v = *reinterpret_cast<const f32x4*>(xa + ((size_t)(row0 + r) * 128 + ci * 8));
        else
            v = f32x4{0.f, 0.f, 0.f, 0.f};
        *reinterpret_cast<f32x4*>(ta + dst) = v;
    }
    ssum[t] = 0.0f;

    // W1 fragments for this wave's two 16-col blocks
    bf16x8 wf[2][4];
#pragma unroll
    for (int nr = 0; nr < 2; ++nr) {
        int nb = 2 * w + nr;
#pragma unroll
        for (int kg = 0; kg < 4; ++kg)
            wf[nr][kg] = *reinterpret_cast<const bf16x8*>(
                wfa + ((size_t)((kg * 8 + nb) * 64 + l)) * 8);
    }
    __syncthreads();

    int rr = l & 15;       // row within 16-tile
    int kg8 = l >> 4;      // k sub-group

    f32x4 acc[4][2];
#pragma unroll
    for (int mr = 0; mr < 4; ++mr)
#pragma unroll
        for (int nr = 0; nr < 2; ++nr)
            acc[mr][nr] = f32x4{0.f, 0.f, 0.f, 0.f};

#pragma unroll
    for (int mr = 0; mr < 4; ++mr) {
        int r = mr * 16 + rr;
        bf16x8 af[4];
#pragma unroll
        for (int kg = 0; kg < 4; ++kg) {
            int idx = (r * 128 + kg * 32 + kg8 * 8) ^ ((r & 7) << 3);
            af[kg] = *reinterpret_cast<const bf16x8*>(ta + idx);
        }
#pragma unroll
        for (int nr = 0; nr < 2; ++nr)
#pragma unroll
            for (int kg = 0; kg < 4; ++kg)
                acc[mr][nr] = __builtin_amdgcn_mfma_f32_16x16x32_bf16(
                    af[kg], wf[nr][kg], acc[mr][nr], 0, 0, 0);
    }

    // bias + relu -> tc (bf16, swizzled)
    int colb = w * 32;
    float b0 = ba[colb + rr];
    float b1 = ba[colb + 16 + rr];
#pragma unroll
    for (int mr = 0; mr < 4; ++mr)
#pragma unroll
        for (int nr = 0; nr < 2; ++nr) {
            float bb_ = nr ? b1 : b0;
            int col = colb + nr * 16 + rr;
#pragma unroll
            for (int reg = 0; reg < 4; ++reg) {
                int row = mr * 16 + kg8 * 4 + reg;
                float v = fmaxf(acc[mr][nr][reg] + bb_, 0.0f);
                tc[(row * 128 + col) ^ ((row & 7) << 3)] = (short)f2bf(v);
            }
        }

    // W2 fragments
#pragma unroll
    for (int nr = 0; nr < 2; ++nr) {
        int nb = 2 * w + nr;
#pragma unroll
        for (int kg = 0; kg < 4; ++kg)
            wf[nr][kg] = *reinterpret_cast<const bf16x8*>(
                wfb + ((size_t)((kg * 8 + nb) * 64 + l)) * 8);
    }
    __syncthreads();

#pragma unroll
    for (int mr = 0; mr < 4; ++mr)
#pragma unroll
        for (int nr = 0; nr < 2; ++nr)
            acc[mr][nr] = f32x4{0.f, 0.f, 0.f, 0.f};

#pragma unroll
    for (int mr = 0; mr < 4; ++mr) {
        int r = mr * 16 + rr;
        bf16x8 af[4];
#pragma unroll
        for (int kg = 0; kg < 4; ++kg) {
            int idx = (r * 128 + kg * 32 + kg8 * 8) ^ ((r & 7) << 3);
            af[kg] = *reinterpret_cast<const bf16x8*>(tc + idx);
        }
#pragma unroll
        for (int nr = 0; nr < 2; ++nr)
#pragma unroll
            for (int kg = 0; kg < 4; ++kg)
                acc[mr][nr] = __builtin_amdgcn_mfma_f32_16x16x32_bf16(
                    af[kg], wf[nr][kg], acc[mr][nr], 0, 0, 0);
    }

    // bias + relu + store + BN stats
    float c0 = bb[colb + rr];
    float c1 = bb[colb + 16 + rr];
    float s0 = 0.f, q0 = 0.f, s1 = 0.f, q1 = 0.f;
#pragma unroll
    for (int mr = 0; mr < 4; ++mr) {
#pragma unroll
        for (int reg = 0; reg < 4; ++reg) {
            int row = row0 + mr * 16 + kg8 * 4 + reg;
            bool ok = row < N;
            float v0 = fmaxf(acc[mr][0][reg] + c0, 0.0f);
            float v1 = fmaxf(acc[mr][1][reg] + c1, 0.0f);
            if (ok) {
                h[(size_t)row * 128 + colb + rr] = v0;
                h[(size_t)row * 128 + colb + 16 + rr] = v1;
                s0 += v0; q0 += v0 * v0;
                s1 += v1; q1 += v1 * v1;
            }
        }
    }
    s0 += __shfl_xor(s0, 16); s0 += __shfl_xor(s0, 32);
    q0 += __shfl_xor(q0, 16); q0 += __shfl_xor(q0, 32);
    s1 += __shfl_xor(s1, 16); s1 += __shfl_xor(s1, 32);
    q1 += __shfl_xor(q1, 16); q1 += __shfl_xor(q1, 32);
    if (kg8 == 0) {
        atomicAdd(&ssum[colb + rr], s0);
        atomicAdd(&ssum[128 + colb + rr], q0);
        atomicAdd(&ssum[colb + 16 + rr], s1);
        atomicAdd(&ssum[128 + colb + 16 + rr], q1);
    }
    __syncthreads();
    atomicAdd(&stats[t], ssum[t]);
}

// ---------------------------------------------------------------------------
// BatchNorm apply (in place) + optional bf16 copy for next layer's gather
// ---------------------------------------------------------------------------
__global__ __launch_bounds__(256) void bn_apply_k(
    float* __restrict__ h, const float* __restrict__ stats,
    const float* __restrict__ gamma, const float* __restrict__ beta,
    u32* __restrict__ hb2, int N)
{
    __shared__ float sc[128], sh[128];
    int t = threadIdx.x;
    if (t < 128) {
        float invN = 1.0f / (float)N;
        float mean = stats[t] * invN;
        float var  = stats[128 + t] * invN - mean * mean;
        float s = gamma[t] * rsqrtf(var + 1e-5f);
        sc[t] = s;
        sh[t] = beta[t] - mean * s;
    }
    __syncthreads();
    int total = N * 32;
    for (int i = blockIdx.x * 256 + t; i < total; i += gridDim.x * 256) {
        float4 v = reinterpret_cast<float4*>(h)[i];
        int c = (i & 31) * 4;
        v.x = v.x * sc[c + 0] + sh[c + 0];
        v.y = v.y * sc[c + 1] + sh[c + 1];
        v.z = v.z * sc[c + 2] + sh[c + 2];
        v.w = v.w * sc[c + 3] + sh[c + 3];
        reinterpret_cast<float4*>(h)[i] = v;
        if (hb2) {
            hb2[2 * i + 0] = pack2(v.x, v.y);
            hb2[2 * i + 1] = pack2(v.z, v.w);
        }
    }
}

// ---------------------------------------------------------------------------
extern "C" void kernel_launch(void* const* d_in, const int* in_sizes, int n_in,
                              void* d_out, int out_size, void* d_ws, size_t ws_size,
                              hipStream_t stream)
{
    const float* x   = (const float*)d_in[0];
    const int*   ei  = (const int*)d_in[1];
    const float* W1a = (const float*)d_in[2];
    const float* b1a = (const float*)d_in[3];
    const float* W1b = (const float*)d_in[4];
    const float* b1b = (const float*)d_in[5];
    const float* g1  = (const float*)d_in[6];
    const float* be1 = (const float*)d_in[7];
    const float* W2a = (const float*)d_in[8];
    const float* b2a = (const float*)d_in[9];
    const float* W2b = (const float*)d_in[10];
    const float* b2b = (const float*)d_in[11];
    const float* g2  = (const float*)d_in[12];
    const float* be2 = (const float*)d_in[13];

    const int N = in_sizes[0] / 128;
    const int E = in_sizes[1] / 2;
    const int* esrc = ei;
    const int* edst = ei + E;

    // ---- workspace carve (large, 256B-aligned chunks first) ----
    char* p = (char*)d_ws;
    const size_t featb = (size_t)N * 128 * sizeof(u16);     // 25.6 MB
    u16* xa = (u16*)p;            p += featb;
    u16* xb = (u16*)p;            p += featb;
    u16* wf = (u16*)p;            p += 4 * 16384 * sizeof(u16);
    int* slots = (int*)p;         p += (size_t)E * sizeof(int);
    int* deg   = (int*)p;         p += (size_t)N * sizeof(int);
    int* offs  = (int*)p;         p += (size_t)N * sizeof(int);
    int* cur   = (int*)p;         p += (size_t)N * sizeof(int);
    int* bsum  = (int*)p;         p += 512 * sizeof(int);
    float* stats = (float*)p;     p += 256 * sizeof(float);

    u16* wf1a = wf;
    u16* wf1b = wf + 16384;
    u16* wf2a = wf + 32768;
    u16* wf2b = wf + 49152;

    float* h = (float*)d_out;
    const int nb = (N + 255) / 256;
    const int eblocks = (E + 255) / 256;
    const int gblocks = (N + 3) / 4;
    const int mblocks = (N + 63) / 64;

    // ---- one-time prep: CSR + bf16 conversions ----
    hipMemsetAsync(deg, 0, (size_t)N * sizeof(int), stream);
    count_k<<<eblocks, 256, 0, stream>>>(edst, deg, E);
    scan1_k<<<nb, 256, 0, stream>>>(deg, offs, bsum, N);
    scan2_k<<<1, 512, 0, stream>>>(bsum, nb);
    scan3_k<<<nb, 256, 0, stream>>>(offs, bsum, cur, N);
    fill_k<<<eblocks, 256, 0, stream>>>(esrc, edst, cur, slots, E);
    convert_k<<<2048, 256, 0, stream>>>(x, (u32*)xb, N * 32);
    wprep_k<<<64, 256, 0, stream>>>(W1a, wf1a);
    wprep_k<<<64, 256, 0, stream>>>(W1b, wf1b);
    wprep_k<<<64, 256, 0, stream>>>(W2a, wf2a);
    wprep_k<<<64, 256, 0, stream>>>(W2b, wf2b);

    // ---- layer 1 ----
    hipMemsetAsync(stats, 0, 256 * sizeof(float), stream);
    gather_k<<<gblocks, 256, 0, stream>>>((const u32*)xb, offs, deg, slots, (u32*)xa, N);
    mlp_mfma_k<<<mblocks, 256, 0, stream>>>(xa, wf1a, b1a, wf1b, b1b, h, stats, N);
    bn_apply_k<<<2048, 256, 0, stream>>>(h, stats, g1, be1, (u32*)xb, N);

    // ---- layer 2 ----
    hipMemsetAsync(stats, 0, 256 * sizeof(float), stream);
    gather_k<<<gblocks, 256, 0, stream>>>((const u32*)xb, offs, deg, slots, (u32*)xa, N);
    mlp_mfma_k<<<mblocks, 256, 0, stream>>>(xa, wf2a, b2a, wf2b, b2b, h, stats, N);
    bn_apply_k<<<2048, 256, 0, stream>>>(h, stats, g2, be2, (u32*)nullptr, N);
}